// Round 8
// baseline (341.626 us; speedup 1.0000x reference)
//
#include <hip/hip_runtime.h>

#define CIN 512
#define HTOT 128
#define WTOT 128
#define HW (HTOT*WTOT)      // 16384
#define SH 64
#define SW 64
#define SHW (SH*SW)         // 4096
#define OCH 3

// clang-native vector type: __builtin_nontemporal_* requires a real vector,
// not HIP's HIP_vector_type<float,4> class.
typedef float vfloat4 __attribute__((ext_vector_type(4)));

// 256 threads = 4 waves. Wave g handles channels [g*128, (g+1)*128).
// Each lane owns a quad of 4 consecutive pixels (vfloat4 per channel).
// Block covers 64 quads = 256 pixels. Grid = 8 batches * 64 = 512 blocks.
__global__ __launch_bounds__(256) void torgb_fused(
    const float* __restrict__ x,
    const float* __restrict__ skip,
    const float* __restrict__ conv_w,
    const float* __restrict__ flr_bias,
    const float* __restrict__ rgb_bias,
    float* __restrict__ out)
{
    __shared__ __align__(16) float wT[CIN][4];  // [c][o], scale folded, 8 KB
    __shared__ float red[256][13];              // partial sums, pad 13 -> no bank conflict

    const int tid = threadIdx.x;
    const int g   = tid >> 6;   // wave id = channel group
    const int qb  = tid & 63;   // quad within block

    // Stage weights transposed into LDS with the EqualConv scale folded in.
    const float scale = 0.04419417382415922f;   // 1/sqrt(512)
    for (int c = tid; c < CIN; c += 256) {
        wT[c][0] = conv_w[          c] * scale;
        wT[c][1] = conv_w[  CIN   + c] * scale;
        wT[c][2] = conv_w[2*CIN   + c] * scale;
        wT[c][3] = 0.0f;
    }
    __syncthreads();

    const int b    = blockIdx.x >> 6;     // batch
    const int blk  = blockIdx.x & 63;     // block within batch
    const int quad = (blk << 6) + qb;     // quad within image
    const int hw   = quad << 2;           // first pixel of quad

    // ---- epilogue geometry + EARLY skip loads (hide HBM latency under conv) ----
    const int y  = hw >> 7;            // row (same for all 4 pixels of quad)
    const int x0 = hw & (WTOT-1);      // first col (multiple of 4)
    const int   i0  = (y - 1) >> 1;    // arithmetic shift: y=0 -> -1 (zero row)
    const float cy0 = (y & 1) ? 0.75f : 0.25f;
    const float cy1 = (y & 1) ? 0.25f : 0.75f;
    const int   jx  = (x0 >> 1) - 1;   // leftmost skip column needed

    const int o = tid >> 6;            // output channel for epilogue waves (0..2)
    float sr[2][4];
    float fb = 0.0f, rb = 0.0f;
    if (o < OCH) {
        const float* sp = skip + ((size_t)b * OCH + o) * SHW;
        #pragma unroll
        for (int r = 0; r < 2; ++r) {
            const int  iy  = i0 + r;
            const bool yok = ((unsigned)iy < SH);
            #pragma unroll
            for (int cI = 0; cI < 4; ++cI) {
                const int ix = jx + cI;
                sr[r][cI] = (yok && (unsigned)ix < SW) ? sp[iy*SW + ix] : 0.0f;
            }
        }
        fb = flr_bias[o];
        rb = rgb_bias[o];
    }

    const vfloat4* xp = (const vfloat4*)(x + ((size_t)b * CIN + (size_t)(g << 7)) * HW + hw);

    float acc[12];
    #pragma unroll
    for (int i = 0; i < 12; ++i) acc[i] = 0.0f;

    const int cbase = g << 7;
    #pragma unroll 8
    for (int cc = 0; cc < 128; ++cc) {
        // x is streamed exactly once -> non-temporal (nt) keeps skip/conv_w hot in L2/L3
        vfloat4 v = __builtin_nontemporal_load(&xp[(size_t)cc * (HW/4)]);
        vfloat4 w = *(const vfloat4*)(&wT[cbase + cc][0]);     // LDS broadcast
        acc[0] += v.x*w.x; acc[1] += v.y*w.x; acc[2] += v.z*w.x; acc[3] += v.w*w.x;
        acc[4] += v.x*w.y; acc[5] += v.y*w.y; acc[6] += v.z*w.y; acc[7] += v.w*w.y;
        acc[8] += v.x*w.z; acc[9] += v.y*w.z; acc[10]+= v.z*w.z; acc[11]+= v.w*w.z;
    }

    #pragma unroll
    for (int i = 0; i < 12; ++i) red[tid][i] = acc[i];
    __syncthreads();

    // ---- epilogue: 3 waves, one output channel each ----
    if (o < OCH) {
        float s[4];
        #pragma unroll
        for (int j = 0; j < 4; ++j) {
            const int i = o * 4 + j;
            s[j] = red[qb][i] + red[64+qb][i] + red[128+qb][i] + red[192+qb][i];
        }

        const float SQRT2 = 1.41421356237309515f;

        // horizontal taps per pixel p (x = x0+p): cols jx+rel0[p], jx+rel0[p]+1
        const int   rel0[4] = {0, 1, 1, 2};
        const float cxa[4]  = {0.25f, 0.75f, 0.25f, 0.75f};
        const float cxb[4]  = {0.75f, 0.25f, 0.75f, 0.25f};

        vfloat4 res;
        #pragma unroll
        for (int p = 0; p < 4; ++p) {
            const float h0 = cxa[p]*sr[0][rel0[p]] + cxb[p]*sr[0][rel0[p]+1];
            const float h1 = cxa[p]*sr[1][rel0[p]] + cxb[p]*sr[1][rel0[p]+1];
            const float up = cy0*h0 + cy1*h1;
            float z = s[p] + fb;
            z = (z >= 0.0f ? z : 0.2f*z) * SQRT2;   // FusedLeakyReLU
            res[p] = z + rb + up;
        }
        // output is write-once -> non-temporal store, don't pollute L2
        __builtin_nontemporal_store(res, (vfloat4*)(out + ((size_t)b * OCH + o) * HW + hw));
    }
}

extern "C" void kernel_launch(void* const* d_in, const int* in_sizes, int n_in,
                              void* d_out, int out_size, void* d_ws, size_t ws_size,
                              hipStream_t stream) {
    const float* x    = (const float*)d_in[0];
    const float* skip = (const float*)d_in[1];
    const float* w    = (const float*)d_in[2];
    const float* fb   = (const float*)d_in[3];
    const float* rb   = (const float*)d_in[4];
    float* out = (float*)d_out;
    torgb_fused<<<dim3(512), dim3(256), 0, stream>>>(x, skip, w, fb, rb, out);
}